// Round 1
// baseline (254.087 us; speedup 1.0000x reference)
//
#include <hip/hip_runtime.h>
#include <hip/hip_bf16.h>

// ---------------------------------------------------------------------------
// LucasKANLayer fused: y[b,o] = sum_i sum_d L_d(tanh(x[b,i])) * C[i,o,d]
// R12 = R11 gemm (verified 137us: dbuf global_load_lds staging, XOR swizzle,
// 1 barrier/step, KSPLIT=2, 4 blocks/CU, wave tile 32m x 128n) + prep split:
//   - R11 prep was ONE dispatch whose 65KiB static LDS (transpose scratch)
//     capped ALL 12800 blocks at 2 blocks/CU; zero/tanh streaming phases ran
//     at ~1.3 TB/s => prep ~107us of the 245us total.
//   - R12: P1 = no-LDS grid-stride zero+tanh (2048 blocks, full occupancy),
//     P2 = transpose alone (its LDS only constrains its own 512 blocks).
//   GEMM kernel byte-identical to R11.
// ---------------------------------------------------------------------------

typedef __attribute__((ext_vector_type(8)))  short  short8;    // bf16x8 MFMA frag
typedef __attribute__((ext_vector_type(4)))  unsigned short ushort4v;
typedef __attribute__((ext_vector_type(8)))  unsigned short ushort8;
typedef __attribute__((ext_vector_type(4)))  float  float4v;
typedef __attribute__((ext_vector_type(4)))  unsigned int uint4v;

#define M_DIM 8192
#define I_DIM 1024
#define O_DIM 1024
#define K_DIM 8192   // I_DIM * 8
#define BM 128
#define BN 128
#define BK 64        // 8 i-values per K-step
#define KSPLIT 2
#define KHALF (K_DIM / KSPLIT)
#define NSTEP (KHALF / BK)   // 64

// round-to-nearest-even fp32 -> bf16 bits (prep kernels)
__device__ __forceinline__ unsigned short f2bf(float f) {
    unsigned int u = __float_as_uint(f);
    u += 0x7FFFu + ((u >> 16) & 1u);
    return (unsigned short)(u >> 16);
}

// ---- P1: zero d_out + tanh->T, grid-stride, NO LDS (full occupancy) ----
// T[b][group g]: slot 2p = t(i=g*8+p), slot 2p+1 = t(i=g*8+p+4): b32 read at
// u16-offset quad*2 gives {lo=t(quad), hi=t(quad+4)}       [R6-verified].
__global__ __launch_bounds__(256) void prep_zt_kernel(const float* __restrict__ x,
                                                      unsigned short* __restrict__ T,
                                                      float* __restrict__ outz) {
    const int nthr = gridDim.x * 256;
    const int gid  = blockIdx.x * 256 + threadIdx.x;

    // zero out: M*O floats = 2,097,152 float4 chunks (4 iters at 2048 blocks)
    const int zN = (M_DIM * O_DIM) / 4;
    const float4v z = {0.f, 0.f, 0.f, 0.f};
    for (int i = gid; i < zN; i += nthr)
        *(float4v*)(outz + (size_t)i * 4) = z;

    // tanh: M*I / 8 = 1,048,576 chunks (2 iters at 2048 blocks)
    const int tN = (M_DIM * I_DIM) / 8;
    for (int i = gid; i < tN; i += nthr) {
        const size_t idx = (size_t)i * 8;
        float4v v0 = *(const float4v*)(x + idx);
        float4v v1 = *(const float4v*)(x + idx + 4);
        unsigned short t[8];
        t[0] = f2bf(tanhf(v0[0])); t[1] = f2bf(tanhf(v0[1]));
        t[2] = f2bf(tanhf(v0[2])); t[3] = f2bf(tanhf(v0[3]));
        t[4] = f2bf(tanhf(v1[0])); t[5] = f2bf(tanhf(v1[1]));
        t[6] = f2bf(tanhf(v1[2])); t[7] = f2bf(tanhf(v1[3]));
        ushort8 o;
        #pragma unroll
        for (int p = 0; p < 4; ++p) { o[2 * p] = t[p]; o[2 * p + 1] = t[p + 4]; }
        *(ushort8*)(T + idx) = o;
    }
}

// ---- P2: B transpose via LDS (tile 64 i x 32 o, coalesced R+W) ----
// Bt[o][i*8+d] = bf16(coeffs[i][o][d])                     [R9-verified].
__global__ __launch_bounds__(256) void prep_tr_kernel(const float* __restrict__ c,
                                                      unsigned short* __restrict__ Bt) {
    __shared__ unsigned short S[32][64 * 8 + 8];
    const int tid = threadIdx.x;
    const int tb  = blockIdx.x;                    // 0..511
    const int i0 = (tb >> 5) * 64;
    const int o0 = (tb & 31) * 32;
    #pragma unroll 4
    for (int p = 0; p < 16; ++p) {
        const int il = p * 4 + (tid >> 6);
        const int e  = (tid & 63) * 4;
        const float* src = c + (size_t)(i0 + il) * 8192 + o0 * 8 + e;
        float4v v = *(const float4v*)src;
        ushort4v u;
        u[0] = f2bf(v[0]); u[1] = f2bf(v[1]); u[2] = f2bf(v[2]); u[3] = f2bf(v[3]);
        *(ushort4v*)&S[e >> 3][il * 8 + (e & 7)] = u;
    }
    __syncthreads();
    #pragma unroll 4
    for (int q = 0; q < 16; ++q) {
        const int ol = q * 2 + (tid >> 7);
        const int ch = (tid & 127) * 4;
        ushort4v u = *(const ushort4v*)&S[ol][ch];
        *(ushort4v*)(Bt + (size_t)(o0 + ol) * K_DIM + i0 * 8 + ch) = u;
    }
}

// Lucas A-fragment {2, t, L2..L7} packed bf16x8 from bf16 t-bits tb (low 16).
__device__ __forceinline__ short8 lucas_frag(unsigned int tb) {
    const float t = __uint_as_float(tb << 16);
    const float L2v = fmaf(t, t, 2.0f);
    const float L3v = fmaf(t, L2v, t);
    const float L4v = fmaf(t, L3v, L2v);
    const float L5v = fmaf(t, L4v, L3v);
    const float L6v = fmaf(t, L5v, L4v);
    const float L7v = fmaf(t, L6v, L5v);
    union { uint4v u; short8 s; } r;
#if __has_builtin(__builtin_amdgcn_cvt_pk_bf16_f32)
    {
        auto p0 = __builtin_amdgcn_cvt_pk_bf16_f32(2.0f, t);
        auto p1 = __builtin_amdgcn_cvt_pk_bf16_f32(L2v, L3v);
        auto p2 = __builtin_amdgcn_cvt_pk_bf16_f32(L4v, L5v);
        auto p3 = __builtin_amdgcn_cvt_pk_bf16_f32(L6v, L7v);
        __builtin_memcpy(&r.u[0], &p0, 4);
        __builtin_memcpy(&r.u[1], &p1, 4);
        __builtin_memcpy(&r.u[2], &p2, 4);
        __builtin_memcpy(&r.u[3], &p3, 4);
    }
#else
    {
        r.u[0] = 0x4000u | (tb << 16);
        r.u[1] = __builtin_amdgcn_perm(__float_as_uint(L3v), __float_as_uint(L2v), 0x07060302);
        r.u[2] = __builtin_amdgcn_perm(__float_as_uint(L5v), __float_as_uint(L4v), 0x07060302);
        r.u[3] = __builtin_amdgcn_perm(__float_as_uint(L7v), __float_as_uint(L6v), 0x07060302);
    }
#endif
    return r.s;
}

// ---- fused GEMM: out[m][n] += sum_{k half} A[m][k] * Bt[n][k] ----
// wave tile 32m x 128n: wave w owns m rows [w*32, w*32+32), all 128 n.
// BYTE-IDENTICAL to R11 (verified 137us, MfmaUtil 46%).
__global__ __launch_bounds__(256, 4) void gemm_kernel(const unsigned short* __restrict__ T,
                                                      const unsigned short* __restrict__ Bt,
                                                      float* __restrict__ out) {
    __shared__ unsigned short Bs[2][BN * BK];   // 32 KB, XOR-swizzled, dbuf
    __shared__ unsigned short Ts[2][BM * 8];    // 4 KB, dbuf (permuted 8-groups)

    const int tid  = threadIdx.x;
    const int lane = tid & 63;
    const int wave = tid >> 6;
    const int n0 = blockIdx.x * BN;        // x = n-panel (8): XCD = linear%8 = x
    const int m0 = blockIdx.y * BM;        // y = m (64)
    const int k0 = blockIdx.z * KHALF;     // z = K half (2)

    const int wm0  = wave * 32;            // wave tile 32m x 128n
    const int l16  = lane & 15;
    const int quad = lane >> 4;

    const int srow   = lane >> 3;          // staging: 0..7
    const int il     = lane & 7;
    const int gchunk = il ^ srow;          // XOR-swizzled global 16B chunk

    float4v acc[2][8];
    const float4v zero = {0.f, 0.f, 0.f, 0.f};
    #pragma unroll
    for (int a = 0; a < 2; ++a)
        #pragma unroll
        for (int b = 0; b < 8; ++b) acc[a][b] = zero;

    // stage one K-step: B 4 insts/wave (8 rows each, 128 total), T wave<2
    auto stage = [&](int buf, int kt) {
        #pragma unroll
        for (int r = 0; r < 4; ++r) {
            const int rowb = r * 32 + wave * 8;
            const unsigned short* gB = Bt + (size_t)(n0 + rowb + srow) * K_DIM + kt + gchunk * 8;
            __builtin_amdgcn_global_load_lds(
                (const __attribute__((address_space(1))) unsigned int*)gB,
                (__attribute__((address_space(3))) unsigned int*)&Bs[buf][rowb * BK], 16, 0, 0);
        }
        if (wave < 2) {
            const unsigned short* gT = T + (size_t)(m0 + wave * 64 + lane) * I_DIM + kt / 8;
            __builtin_amdgcn_global_load_lds(
                (const __attribute__((address_space(1))) unsigned int*)gT,
                (__attribute__((address_space(3))) unsigned int*)&Ts[buf][wave * 64 * 8], 16, 0, 0);
        }
    };

    stage(0, k0);
    __syncthreads();

    int cur = 0;
    for (int s = 0; s < NSTEP; ++s) {
        const int nxt = cur ^ 1;
        if (s + 1 < NSTEP) stage(nxt, k0 + (s + 1) * BK);

        // t-words: one b32 per m-tile {lo=t(quad)->k2=0, hi=t(quad+4)->k2=1}
        unsigned int tw[2];
        #pragma unroll
        for (int tt = 0; tt < 2; ++tt)
            tw[tt] = *(const unsigned int*)&Ts[cur][(wm0 + tt * 16 + l16) * 8 + quad * 2];

        #pragma unroll
        for (int k2 = 0; k2 < 2; ++k2) {
            short8 af[2];
            af[0] = lucas_frag(k2 ? (tw[0] >> 16) : (tw[0] & 0xffffu));
            af[1] = lucas_frag(k2 ? (tw[1] >> 16) : (tw[1] & 0xffffu));
            #pragma unroll
            for (int g = 0; g < 2; ++g) {          // n-halves: <=4 live b-frags
                short8 bfr[4];
                #pragma unroll
                for (int j = 0; j < 4; ++j) {
                    const int brow = (g * 4 + j) * 16 + l16;
                    bfr[j] = *(const short8*)&Bs[cur][brow * BK + (((k2 * 4 + quad) ^ (l16 & 7)) * 8)];
                }
                #pragma unroll
                for (int tt = 0; tt < 2; ++tt)
                    #pragma unroll
                    for (int j = 0; j < 4; ++j)
                        acc[tt][g * 4 + j] = __builtin_amdgcn_mfma_f32_16x16x32_bf16(
                            af[tt], bfr[j], acc[tt][g * 4 + j], 0, 0, 0);
            }
        }

        __syncthreads();   // drains prefetch + protects Bs/Ts swap
        cur = nxt;
    }

    // epilogue: D[row=(lane>>4)*4+r][col=lane&15] (verified R1-R9)
    #pragma unroll
    for (int tt = 0; tt < 2; ++tt) {
        #pragma unroll
        for (int tn = 0; tn < 8; ++tn) {
            const int col = n0 + tn * 16 + l16;
            #pragma unroll
            for (int r = 0; r < 4; ++r) {
                const int row = m0 + wm0 + tt * 16 + quad * 4 + r;
                atomicAdd(&out[(size_t)row * O_DIM + col], acc[tt][tn][r]);
            }
        }
    }
}

// ---- fallback (tiny workspace): direct fp32 ----
__global__ __launch_bounds__(256) void naive_kernel(const float* __restrict__ x,
                                                    const float* __restrict__ c,
                                                    float* __restrict__ out) {
    int idx = blockIdx.x * 256 + threadIdx.x;   // one (b,o)
    int b = idx >> 10;
    int o = idx & 1023;
    const float* xb = x + (size_t)b * I_DIM;
    float acc = 0.f;
    for (int i = 0; i < I_DIM; ++i) {
        float t = tanhf(xb[i]);
        float L[8];
        L[0] = 2.0f; L[1] = t;
        #pragma unroll
        for (int d = 2; d < 8; ++d) L[d] = t * L[d - 1] + L[d - 2];
        const float* cc = c + (size_t)i * 8192 + o * 8;
        #pragma unroll
        for (int d = 0; d < 8; ++d) acc += L[d] * cc[d];
    }
    out[idx] = acc;
}

extern "C" void kernel_launch(void* const* d_in, const int* in_sizes, int n_in,
                              void* d_out, int out_size, void* d_ws, size_t ws_size,
                              hipStream_t stream) {
    const float* x      = (const float*)d_in[0];
    const float* coeffs = (const float*)d_in[1];
    float* out = (float*)d_out;

    const size_t btBytes = (size_t)O_DIM * K_DIM * sizeof(unsigned short);   // 16 MiB
    const size_t tBytes  = (size_t)M_DIM * I_DIM * sizeof(unsigned short);   // 16 MiB

    if (ws_size >= btBytes + tBytes) {
        unsigned short* Bt = (unsigned short*)d_ws;
        unsigned short* T  = (unsigned short*)((char*)d_ws + btBytes);

        const int xBlocks = (I_DIM / 64) * (I_DIM / 32);   // 512 transpose tiles
        prep_tr_kernel<<<xBlocks, 256, 0, stream>>>(coeffs, Bt);
        prep_zt_kernel<<<2048, 256, 0, stream>>>(x, T, out);

        dim3 grid(O_DIM / BN, M_DIM / BM, KSPLIT);   // (8, 64, 2): XCD = x
        gemm_kernel<<<grid, 256, 0, stream>>>(T, Bt, out);
    } else {
        naive_kernel<<<(M_DIM * O_DIM) / 256, 256, 0, stream>>>(x, coeffs, out);
    }
}